// Round 4
// baseline (2936.458 us; speedup 1.0000x reference)
//
#include <hip/hip_runtime.h>
#include <stdint.h>

// Disable automatic FP contraction file-wide: the uncertainty path must be
// bit-identical to the JAX/numpy reference (mul+add, no fused fma), because
// it drives top-k SELECTION ORDER. Explicit fmaf() in the GEMM is unaffected.
#pragma clang fp contract(off)

// RNG_MODE: 0 = original threefry random_bits (halved iota), 1 = partitionable
// (per-element 64-bit counter, bits = out0 ^ out1). Modern JAX defaults to 1.
// Round-1 failure (absmax 0.999 on coords incl. the pure-random tail) showed
// "low word only" was wrong; partitionable path XORs both output words.
#define RNG_MODE 1

#define NB    8
#define CCH   19
#define FCH   256
#define FIN   275      // 256 + 19
#define NPTS  16384
#define NSAMP 49152    // 3x oversample
#define NIMP  12288
#define NRAND 4096
#define SORT_M 65536
#define CHUNK  8192
#define TP    32       // points per block in fused head

// ---------------- threefry2x32 (exact JAX algorithm) ----------------
__host__ __device__ __forceinline__ uint32_t rotl32(uint32_t v, int r) {
  return (v << r) | (v >> (32 - r));
}

__host__ __device__ __forceinline__ void tf2x32(uint32_t k0, uint32_t k1,
                                                uint32_t x0, uint32_t x1,
                                                uint32_t* o0, uint32_t* o1) {
  const uint32_t ks2 = k0 ^ k1 ^ 0x1BD11BDAu;
  x0 += k0; x1 += k1;
#define TF_R(r) { x0 += x1; x1 = rotl32(x1, (r)); x1 ^= x0; }
  TF_R(13) TF_R(15) TF_R(26) TF_R(6)
  x0 += k1;  x1 += ks2 + 1u;
  TF_R(17) TF_R(29) TF_R(16) TF_R(24)
  x0 += ks2; x1 += k0 + 2u;
  TF_R(13) TF_R(15) TF_R(26) TF_R(6)
  x0 += k0;  x1 += k1 + 3u;
  TF_R(17) TF_R(29) TF_R(16) TF_R(24)
  x0 += k1;  x1 += ks2 + 4u;
  TF_R(13) TF_R(15) TF_R(26) TF_R(6)
  x0 += ks2; x1 += k0 + 5u;
#undef TF_R
  *o0 = x0; *o1 = x1;
}

__device__ __forceinline__ float u01(uint32_t b) {
  // JAX _uniform: bitcast(bits>>9 | 0x3f800000) - 1.0, then max(0, .)
  const float f = __uint_as_float((b >> 9) | 0x3f800000u) - 1.0f;
  return fmaxf(0.0f, f);
}

// partitionable: bits[i] = o0 ^ o1 of tf(key, (hi(i)=0, lo(i)=i))
__global__ __launch_bounds__(256) void gen_uniform_part(float* __restrict__ out,
                                                        unsigned n, uint32_t k0, uint32_t k1) {
  const unsigned i = blockIdx.x * blockDim.x + threadIdx.x;
  if (i >= n) return;
  uint32_t o0, o1;
  tf2x32(k0, k1, 0u, i, &o0, &o1);
  out[i] = u01(o0 ^ o1);
}

// original: counts=iota(n); halves; bits[j]=out0, bits[j+H]=out1
__global__ __launch_bounds__(256) void gen_uniform_orig(float* __restrict__ out,
                                                        unsigned half, uint32_t k0, uint32_t k1) {
  const unsigned j = blockIdx.x * blockDim.x + threadIdx.x;
  if (j >= half) return;
  uint32_t o0, o1;
  tf2x32(k0, k1, j, j + half, &o0, &o1);
  out[j] = u01(o0);
  out[j + half] = u01(o1);
}

// ---------------- uncertainty at candidates -> sortable keys ----------------
__global__ __launch_bounds__(256) void unc_keys(const float* __restrict__ coarse,
                                                const float* __restrict__ cand,
                                                unsigned long long* __restrict__ keys) {
  const int tid = blockIdx.x * blockDim.x + threadIdx.x;
  if (tid >= NB * SORT_M) return;
  const int nn = tid >> 16, s = tid & (SORT_M - 1);
  if (s >= NSAMP) { keys[tid] = 0xFFFFFFFFFFFFFFFFull; return; }  // pad sorts last
  const size_t ci = ((size_t)nn * NSAMP + s) * 2;
  const float cx = cand[ci], cy = cand[ci + 1];
  const float X = cx * 64.0f - 0.5f, Y = cy * 64.0f - 0.5f;
  const float x0f = floorf(X), y0f = floorf(Y);
  const float fx = X - x0f, fy = Y - y0f;        // wx1, wy1
  const float wx0 = 1.0f - fx, wy0 = 1.0f - fy;
  const int x0 = (int)x0f, y0 = (int)y0f;
  const int x0c = min(max(x0, 0), 63), x1c = min(max(x0 + 1, 0), 63);
  const int y0c = min(max(y0, 0), 63), y1c = min(max(y0 + 1, 0), 63);
  const bool vx0 = (x0 >= 0) & (x0 <= 63), vx1 = (x0 >= -1) & (x0 <= 62);
  const bool vy0 = (y0 >= 0) & (y0 <= 63), vy1 = (y0 >= -1) & (y0 <= 62);
  // validity folded as exact x1.0/x0.0; product order mirrors reference (wy*wx)
  const float w00 = (vy0 & vx0) ? wy0 * wx0 : 0.0f;
  const float w01 = (vy0 & vx1) ? wy0 * fx  : 0.0f;
  const float w10 = (vy1 & vx0) ? fy  * wx0 : 0.0f;
  const float w11 = (vy1 & vx1) ? fy  * fx  : 0.0f;
  const int o00 = y0c * 64 + x0c, o01 = y0c * 64 + x1c;
  const int o10 = y1c * 64 + x0c, o11 = y1c * 64 + x1c;
  const float* cb = coarse + (size_t)nn * (CCH * 4096);
  float m1 = -3.402823466e38f, m2 = -3.402823466e38f;
  for (int c = 0; c < CCH; ++c) {
    const float* pch = cb + (size_t)c * 4096;
    // exact left-assoc sum matching reference, no contraction (file pragma)
    const float v = ((pch[o00] * w00 + pch[o01] * w01) + pch[o10] * w10) + pch[o11] * w11;
    if (v > m1) { m2 = m1; m1 = v; } else if (v > m2) { m2 = v; }
  }
  const float unc = m2 - m1;   // <= 0
  const uint32_t b = __float_as_uint(unc);
  const uint32_t asc = (b & 0x80000000u) ? ~b : (b | 0x80000000u);
  keys[tid] = ((unsigned long long)(~asc) << 32) | (uint32_t)s;  // asc sort => val desc, idx asc
}

// ---------------- bitonic sort (per batch of 65536 u64 keys) ----------------
__global__ __launch_bounds__(1024) void bitonic_local(unsigned long long* __restrict__ keys) {
  __shared__ unsigned long long s[CHUNK];   // 64 KiB
  const int cb = blockIdx.x;                // 8 chunks per batch, 64 total
  unsigned long long* a = keys + (size_t)cb * CHUNK;
  const unsigned gbase = (unsigned)(cb * CHUNK) & (SORT_M - 1);
  for (int i = threadIdx.x; i < CHUNK; i += 1024) s[i] = a[i];
  __syncthreads();
  for (int k = 2; k <= CHUNK; k <<= 1) {
    for (int j = k >> 1; j > 0; j >>= 1) {
      for (int pid = threadIdx.x; pid < CHUNK / 2; pid += 1024) {
        const int i = ((pid & ~(j - 1)) << 1) | (pid & (j - 1));
        const int l = i | j;
        const bool up = (((gbase + i) & k) == 0);
        const unsigned long long x = s[i], y = s[l];
        if ((x > y) == up) { s[i] = y; s[l] = x; }
      }
      __syncthreads();
    }
  }
  for (int i = threadIdx.x; i < CHUNK; i += 1024) a[i] = s[i];
}

__global__ __launch_bounds__(256) void bitonic_global(unsigned long long* __restrict__ keys,
                                                      int k, int j) {
  const int t = blockIdx.x * blockDim.x + threadIdx.x;   // 8 * 32768 pairs
  const int b = t >> 15, pid = t & 32767;
  const int i = ((pid & ~(j - 1)) << 1) | (pid & (j - 1));
  const int l = i | j;
  const bool up = ((i & k) == 0);
  unsigned long long* a = keys + ((size_t)b << 16);
  const unsigned long long x = a[i], y = a[l];
  if ((x > y) == up) { a[i] = y; a[l] = x; }
}

__global__ __launch_bounds__(1024) void bitonic_finish(unsigned long long* __restrict__ keys,
                                                       int k) {
  __shared__ unsigned long long s[CHUNK];
  const int cb = blockIdx.x;
  unsigned long long* a = keys + (size_t)cb * CHUNK;
  const unsigned gi0 = (unsigned)(cb * CHUNK) & (SORT_M - 1);
  for (int i = threadIdx.x; i < CHUNK; i += 1024) s[i] = a[i];
  __syncthreads();
  const bool up = ((gi0 & k) == 0);   // k > CHUNK => direction constant per chunk
  for (int j = CHUNK >> 1; j > 0; j >>= 1) {
    for (int pid = threadIdx.x; pid < CHUNK / 2; pid += 1024) {
      const int i = ((pid & ~(j - 1)) << 1) | (pid & (j - 1));
      const int l = i | j;
      const unsigned long long x = s[i], y = s[l];
      if ((x > y) == up) { s[i] = y; s[l] = x; }
    }
    __syncthreads();
  }
  for (int i = threadIdx.x; i < CHUNK; i += 1024) a[i] = s[i];
}

// ---------------- write point_coords = [imp(12288), rand(4096)] ----------------
__global__ __launch_bounds__(256) void write_coords(const unsigned long long* __restrict__ keys,
                                                    const float* __restrict__ cand,
                                                    const float* __restrict__ rnd,
                                                    float* __restrict__ outc) {
  const int t = blockIdx.x * blockDim.x + threadIdx.x;
  if (t >= NB * NPTS) return;
  const int nn = t >> 14, p = t & (NPTS - 1);
  float cx, cy;
  if (p < NIMP) {
    const unsigned idx = (unsigned)(keys[((size_t)nn << 16) + p] & 0xFFFFFFFFu);
    const size_t ci = ((size_t)nn * NSAMP + idx) * 2;
    cx = cand[ci]; cy = cand[ci + 1];
  } else {
    const size_t ri = ((size_t)nn * NRAND + (p - NIMP)) * 2;
    cx = rnd[ri]; cy = rnd[ri + 1];
  }
  outc[(size_t)t * 2] = cx;
  outc[(size_t)t * 2 + 1] = cy;
}

// ---------------- fused sample (fine+coarse) + 3-layer MLP + head ----------------
__global__ __launch_bounds__(256, 2) void fused_head(
    const float* __restrict__ coarse, const float* __restrict__ feats,
    const float* __restrict__ w0, const float* __restrict__ b0,
    const float* __restrict__ w1, const float* __restrict__ b1,
    const float* __restrict__ w2, const float* __restrict__ b2,
    const float* __restrict__ wp, const float* __restrict__ bp,
    const float* __restrict__ pc, float* __restrict__ outl) {
  __shared__ __align__(16) float xb[FIN][TP];     // 35.2 KB activations [275][32]
  __shared__ __align__(16) float wT[16][264];     // 16.9 KB weight chunk, stride 264 for b128 align
  __shared__ int   offF[4][TP];
  __shared__ float wgtF[4][TP];
  __shared__ int   offC[4][TP];
  __shared__ float wgtC[4][TP];

  const int t = threadIdx.x;
  const int nn = blockIdx.x >> 9;               // 512 blocks per batch
  const int pbase = (blockIdx.x & 511) * TP;

  if (t < TP) {
    const int p = t;
    const size_t ci = ((size_t)nn * NPTS + pbase + p) * 2;
    const float cx = pc[ci], cy = pc[ci + 1];
    {  // fine grid 128x128
      const float X = cx * 128.0f - 0.5f, Y = cy * 128.0f - 0.5f;
      const float x0f = floorf(X), y0f = floorf(Y);
      const float fx = X - x0f, fy = Y - y0f;
      const float wx0 = 1.0f - fx, wy0 = 1.0f - fy;
      const int x0 = (int)x0f, y0 = (int)y0f;
      const int x0c = min(max(x0, 0), 127), x1c = min(max(x0 + 1, 0), 127);
      const int y0c = min(max(y0, 0), 127), y1c = min(max(y0 + 1, 0), 127);
      const bool vx0 = (x0 >= 0) & (x0 <= 127), vx1 = (x0 >= -1) & (x0 <= 126);
      const bool vy0 = (y0 >= 0) & (y0 <= 127), vy1 = (y0 >= -1) & (y0 <= 126);
      offF[0][p] = y0c * 128 + x0c; wgtF[0][p] = (vy0 & vx0) ? wy0 * wx0 : 0.0f;
      offF[1][p] = y0c * 128 + x1c; wgtF[1][p] = (vy0 & vx1) ? wy0 * fx  : 0.0f;
      offF[2][p] = y1c * 128 + x0c; wgtF[2][p] = (vy1 & vx0) ? fy  * wx0 : 0.0f;
      offF[3][p] = y1c * 128 + x1c; wgtF[3][p] = (vy1 & vx1) ? fy  * fx  : 0.0f;
    }
    {  // coarse grid 64x64
      const float X = cx * 64.0f - 0.5f, Y = cy * 64.0f - 0.5f;
      const float x0f = floorf(X), y0f = floorf(Y);
      const float fx = X - x0f, fy = Y - y0f;
      const float wx0 = 1.0f - fx, wy0 = 1.0f - fy;
      const int x0 = (int)x0f, y0 = (int)y0f;
      const int x0c = min(max(x0, 0), 63), x1c = min(max(x0 + 1, 0), 63);
      const int y0c = min(max(y0, 0), 63), y1c = min(max(y0 + 1, 0), 63);
      const bool vx0 = (x0 >= 0) & (x0 <= 63), vx1 = (x0 >= -1) & (x0 <= 62);
      const bool vy0 = (y0 >= 0) & (y0 <= 63), vy1 = (y0 >= -1) & (y0 <= 62);
      offC[0][p] = y0c * 64 + x0c; wgtC[0][p] = (vy0 & vx0) ? wy0 * wx0 : 0.0f;
      offC[1][p] = y0c * 64 + x1c; wgtC[1][p] = (vy0 & vx1) ? wy0 * fx  : 0.0f;
      offC[2][p] = y1c * 64 + x0c; wgtC[2][p] = (vy1 & vx0) ? fy  * wx0 : 0.0f;
      offC[3][p] = y1c * 64 + x1c; wgtC[3][p] = (vy1 & vx1) ? fy  * fx  : 0.0f;
    }
  }
  __syncthreads();

  {  // fill fine channels
    const float* fb0 = feats + ((size_t)nn << 22);
    for (int i = t; i < FCH * TP; i += 256) {
      const int c = i >> 5, p = i & 31;
      const float* fb = fb0 + ((size_t)c << 14);
      xb[c][p] = ((fb[offF[0][p]] * wgtF[0][p] + fb[offF[1][p]] * wgtF[1][p])
                 + fb[offF[2][p]] * wgtF[2][p]) + fb[offF[3][p]] * wgtF[3][p];
    }
  }
  {  // fill coarse channels
    const float* cb0 = coarse + (size_t)nn * (CCH * 4096);
    for (int i = t; i < CCH * TP; i += 256) {
      const int c = i >> 5, p = i & 31;
      const float* cb = cb0 + (size_t)c * 4096;
      xb[FCH + c][p] = ((cb[offC[0][p]] * wgtC[0][p] + cb[offC[1][p]] * wgtC[1][p])
                       + cb[offC[2][p]] * wgtC[2][p]) + cb[offC[3][p]] * wgtC[3][p];
    }
  }

  const int og = t >> 3;   // 0..31 -> 8 output channels each
  const int pg = t & 7;    // 0..7  -> 4 points each

  const float* Ws[3] = {w0, w1, w2};
  const float* Bs[3] = {b0, b1, b2};

  for (int L = 0; L < 3; ++L) {
    const float* __restrict__ W = Ws[L];
    float acc[8][4];
#pragma unroll
    for (int k = 0; k < 8; ++k)
#pragma unroll
      for (int j = 0; j < 4; ++j) acc[k][j] = 0.0f;

    for (int c0 = 0; c0 < FIN; c0 += 16) {
      const int CCc = min(16, FIN - c0);
      __syncthreads();   // protect wT reuse
      for (int i = t; i < 16 * 256; i += 256) {
        const int cc = i & 15, o = i >> 4;
        const int c = c0 + cc;
        wT[cc][o] = (c < FIN) ? W[o * FIN + c] : 0.0f;
      }
      __syncthreads();
      for (int cc = 0; cc < CCc; ++cc) {
        const float4 xv = *(const float4*)&xb[c0 + cc][pg << 2];
        const float4 wa = *(const float4*)&wT[cc][og << 3];
        const float4 wb = *(const float4*)&wT[cc][(og << 3) + 4];
        const float wv[8] = {wa.x, wa.y, wa.z, wa.w, wb.x, wb.y, wb.z, wb.w};
        const float xv4[4] = {xv.x, xv.y, xv.z, xv.w};
#pragma unroll
        for (int k = 0; k < 8; ++k)
#pragma unroll
          for (int j = 0; j < 4; ++j)
            acc[k][j] = fmaf(wv[k], xv4[j], acc[k][j]);
      }
    }
    __syncthreads();   // everyone done reading xb
    const float* __restrict__ Bv = Bs[L];
#pragma unroll
    for (int k = 0; k < 8; ++k) {
      const float bv = Bv[(og << 3) + k];
      float4 r;
      r.x = fmaxf(acc[k][0] + bv, 0.0f);
      r.y = fmaxf(acc[k][1] + bv, 0.0f);
      r.z = fmaxf(acc[k][2] + bv, 0.0f);
      r.w = fmaxf(acc[k][3] + bv, 0.0f);
      *(float4*)&xb[(og << 3) + k][pg << 2] = r;
    }
    __syncthreads();
  }

  // final 19-ch head
  for (int i = t; i < CCH * TP; i += 256) {
    const int o = i >> 5, p = i & 31;
    float acc = bp[o];
    const float* wr = wp + o * FIN;
    for (int c = 0; c < FIN; ++c) acc = fmaf(wr[c], xb[c][p], acc);
    outl[((size_t)nn * CCH + o) * NPTS + pbase + p] = acc;
  }
}

// ---------------- launcher ----------------
extern "C" void kernel_launch(void* const* d_in, const int* in_sizes, int n_in,
                              void* d_out, int out_size, void* d_ws, size_t ws_size,
                              hipStream_t stream) {
  const float* coarse = (const float*)d_in[0];
  const float* feats  = (const float*)d_in[1];
  const float* w0 = (const float*)d_in[2]; const float* b0 = (const float*)d_in[3];
  const float* w1 = (const float*)d_in[4]; const float* b1 = (const float*)d_in[5];
  const float* w2 = (const float*)d_in[6]; const float* b2 = (const float*)d_in[7];
  const float* wp = (const float*)d_in[8]; const float* bp = (const float*)d_in[9];

  float* out0 = (float*)d_out;                     // (8,19,64,64) passthrough
  float* outL = out0 + 622592;                     // (8,19,16384) point_logits
  float* outC = outL + 2490368;                    // (8,16384,2) point_coords

  float* cand = (float*)d_ws;                      // 786432 f32
  float* rnd  = cand + 786432;                     // 65536 f32
  unsigned long long* keys =
      (unsigned long long*)((char*)d_ws + 3407872);  // 8*65536 u64

  // host-side split of jax.random.key(7) = (0,7)
  uint32_t k1a, k1b, k2a, k2b;
#if RNG_MODE == 0
  // original: counts iota(4) -> pairs (0,2),(1,3); reshape(2,2)
  uint32_t f0, s0, f1, s1;
  tf2x32(0u, 7u, 0u, 2u, &f0, &s0);
  tf2x32(0u, 7u, 1u, 3u, &f1, &s1);
  k1a = f0; k1b = f1; k2a = s0; k2b = s1;
#else
  // partitionable: key_i = both words of tf(key, (0, i)) (foldlike split)
  tf2x32(0u, 7u, 0u, 0u, &k1a, &k1b);
  tf2x32(0u, 7u, 0u, 1u, &k2a, &k2b);
#endif

  hipMemcpyAsync(out0, coarse, 622592 * sizeof(float),
                 hipMemcpyDeviceToDevice, stream);

#if RNG_MODE == 0
  gen_uniform_orig<<<(393216 + 255) / 256, 256, 0, stream>>>(cand, 393216u, k1a, k1b);
  gen_uniform_orig<<<(32768 + 255) / 256, 256, 0, stream>>>(rnd, 32768u, k2a, k2b);
#else
  gen_uniform_part<<<786432 / 256, 256, 0, stream>>>(cand, 786432u, k1a, k1b);
  gen_uniform_part<<<65536 / 256, 256, 0, stream>>>(rnd, 65536u, k2a, k2b);
#endif

  unc_keys<<<2048, 256, 0, stream>>>(coarse, cand, keys);

  bitonic_local<<<64, 1024, 0, stream>>>(keys);
  bitonic_global<<<1024, 256, 0, stream>>>(keys, 16384, 8192);
  bitonic_finish<<<64, 1024, 0, stream>>>(keys, 16384);
  bitonic_global<<<1024, 256, 0, stream>>>(keys, 32768, 16384);
  bitonic_global<<<1024, 256, 0, stream>>>(keys, 32768, 8192);
  bitonic_finish<<<64, 1024, 0, stream>>>(keys, 32768);
  bitonic_global<<<1024, 256, 0, stream>>>(keys, 65536, 32768);
  bitonic_global<<<1024, 256, 0, stream>>>(keys, 65536, 16384);
  bitonic_global<<<1024, 256, 0, stream>>>(keys, 65536, 8192);
  bitonic_finish<<<64, 1024, 0, stream>>>(keys, 65536);

  write_coords<<<512, 256, 0, stream>>>(keys, cand, rnd, outC);

  fused_head<<<4096, 256, 0, stream>>>(coarse, feats, w0, b0, w1, b1, w2, b2,
                                       wp, bp, outC, outL);
}

// Round 5
// 667.083 us; speedup vs baseline: 4.4019x; 4.4019x over previous
//
#include <hip/hip_runtime.h>
#include <stdint.h>

// Contraction off file-wide: the uncertainty path drives top-k SELECTION ORDER
// and must be bit-identical to the JAX/numpy reference (mul+add, no fma).
#pragma clang fp contract(off)

#define RNG_MODE 1

#define NB    8
#define CCH   19
#define FCH   256
#define FIN   275
#define KP    288      // K padded to 9*32
#define NPTS  16384
#define NSAMP 49152
#define NIMP  12288
#define NRAND 4096
#define SORT_M 65536
#define CHUNK  8192
#define TP    64       // points per block in fused MFMA head
#define XROW  640      // bytes per xp row (320 bf16), 128B-multiple for swizzle

typedef __attribute__((ext_vector_type(8))) short bf16x8;
typedef __attribute__((ext_vector_type(4))) float f32x4;

// ---------------- threefry2x32 (exact JAX algorithm) ----------------
__host__ __device__ __forceinline__ uint32_t rotl32(uint32_t v, int r) {
  return (v << r) | (v >> (32 - r));
}

__host__ __device__ __forceinline__ void tf2x32(uint32_t k0, uint32_t k1,
                                                uint32_t x0, uint32_t x1,
                                                uint32_t* o0, uint32_t* o1) {
  const uint32_t ks2 = k0 ^ k1 ^ 0x1BD11BDAu;
  x0 += k0; x1 += k1;
#define TF_R(r) { x0 += x1; x1 = rotl32(x1, (r)); x1 ^= x0; }
  TF_R(13) TF_R(15) TF_R(26) TF_R(6)
  x0 += k1;  x1 += ks2 + 1u;
  TF_R(17) TF_R(29) TF_R(16) TF_R(24)
  x0 += ks2; x1 += k0 + 2u;
  TF_R(13) TF_R(15) TF_R(26) TF_R(6)
  x0 += k0;  x1 += k1 + 3u;
  TF_R(17) TF_R(29) TF_R(16) TF_R(24)
  x0 += k1;  x1 += ks2 + 4u;
  TF_R(13) TF_R(15) TF_R(26) TF_R(6)
  x0 += ks2; x1 += k0 + 5u;
#undef TF_R
  *o0 = x0; *o1 = x1;
}

__device__ __forceinline__ float u01(uint32_t b) {
  const float f = __uint_as_float((b >> 9) | 0x3f800000u) - 1.0f;
  return fmaxf(0.0f, f);
}

__device__ __forceinline__ unsigned short f2bf(float f) {
  // round-to-nearest-even fp32 -> bf16
  const uint32_t u = __float_as_uint(f);
  return (unsigned short)((u + 0x7fffu + ((u >> 16) & 1u)) >> 16);
}

__global__ __launch_bounds__(256) void gen_uniform_part(float* __restrict__ out,
                                                        unsigned n, uint32_t k0, uint32_t k1) {
  const unsigned i = blockIdx.x * blockDim.x + threadIdx.x;
  if (i >= n) return;
  uint32_t o0, o1;
  tf2x32(k0, k1, 0u, i, &o0, &o1);
  out[i] = u01(o0 ^ o1);
}

__global__ __launch_bounds__(256) void gen_uniform_orig(float* __restrict__ out,
                                                        unsigned half, uint32_t k0, uint32_t k1) {
  const unsigned j = blockIdx.x * blockDim.x + threadIdx.x;
  if (j >= half) return;
  uint32_t o0, o1;
  tf2x32(k0, k1, j, j + half, &o0, &o1);
  out[j] = u01(o0);
  out[j + half] = u01(o1);
}

// ---------------- uncertainty at candidates -> sortable keys ----------------
__global__ __launch_bounds__(256) void unc_keys(const float* __restrict__ coarse,
                                                const float* __restrict__ cand,
                                                unsigned long long* __restrict__ keys) {
  const int tid = blockIdx.x * blockDim.x + threadIdx.x;
  if (tid >= NB * SORT_M) return;
  const int nn = tid >> 16, s = tid & (SORT_M - 1);
  if (s >= NSAMP) { keys[tid] = 0xFFFFFFFFFFFFFFFFull; return; }
  const size_t ci = ((size_t)nn * NSAMP + s) * 2;
  const float cx = cand[ci], cy = cand[ci + 1];
  const float X = cx * 64.0f - 0.5f, Y = cy * 64.0f - 0.5f;
  const float x0f = floorf(X), y0f = floorf(Y);
  const float fx = X - x0f, fy = Y - y0f;
  const float wx0 = 1.0f - fx, wy0 = 1.0f - fy;
  const int x0 = (int)x0f, y0 = (int)y0f;
  const int x0c = min(max(x0, 0), 63), x1c = min(max(x0 + 1, 0), 63);
  const int y0c = min(max(y0, 0), 63), y1c = min(max(y0 + 1, 0), 63);
  const bool vx0 = (x0 >= 0) & (x0 <= 63), vx1 = (x0 >= -1) & (x0 <= 62);
  const bool vy0 = (y0 >= 0) & (y0 <= 63), vy1 = (y0 >= -1) & (y0 <= 62);
  const float w00 = (vy0 & vx0) ? wy0 * wx0 : 0.0f;
  const float w01 = (vy0 & vx1) ? wy0 * fx  : 0.0f;
  const float w10 = (vy1 & vx0) ? fy  * wx0 : 0.0f;
  const float w11 = (vy1 & vx1) ? fy  * fx  : 0.0f;
  const int o00 = y0c * 64 + x0c, o01 = y0c * 64 + x1c;
  const int o10 = y1c * 64 + x0c, o11 = y1c * 64 + x1c;
  const float* cb = coarse + (size_t)nn * (CCH * 4096);
  float m1 = -3.402823466e38f, m2 = -3.402823466e38f;
  for (int c = 0; c < CCH; ++c) {
    const float* pch = cb + (size_t)c * 4096;
    const float v = ((pch[o00] * w00 + pch[o01] * w01) + pch[o10] * w10) + pch[o11] * w11;
    if (v > m1) { m2 = m1; m1 = v; } else if (v > m2) { m2 = v; }
  }
  const float unc = m2 - m1;
  const uint32_t b = __float_as_uint(unc);
  const uint32_t asc = (b & 0x80000000u) ? ~b : (b | 0x80000000u);
  keys[tid] = ((unsigned long long)(~asc) << 32) | (uint32_t)s;
}

// ---------------- bitonic sort (per batch of 65536 u64 keys) ----------------
__global__ __launch_bounds__(1024) void bitonic_local(unsigned long long* __restrict__ keys) {
  __shared__ unsigned long long s[CHUNK];
  const int cb = blockIdx.x;
  unsigned long long* a = keys + (size_t)cb * CHUNK;
  const unsigned gbase = (unsigned)(cb * CHUNK) & (SORT_M - 1);
  for (int i = threadIdx.x; i < CHUNK; i += 1024) s[i] = a[i];
  __syncthreads();
  for (int k = 2; k <= CHUNK; k <<= 1) {
    for (int j = k >> 1; j > 0; j >>= 1) {
      for (int pid = threadIdx.x; pid < CHUNK / 2; pid += 1024) {
        const int i = ((pid & ~(j - 1)) << 1) | (pid & (j - 1));
        const int l = i | j;
        const bool up = (((gbase + i) & k) == 0);
        const unsigned long long x = s[i], y = s[l];
        if ((x > y) == up) { s[i] = y; s[l] = x; }
      }
      __syncthreads();
    }
  }
  for (int i = threadIdx.x; i < CHUNK; i += 1024) a[i] = s[i];
}

__global__ __launch_bounds__(256) void bitonic_global(unsigned long long* __restrict__ keys,
                                                      int k, int j) {
  const int t = blockIdx.x * blockDim.x + threadIdx.x;
  const int b = t >> 15, pid = t & 32767;
  const int i = ((pid & ~(j - 1)) << 1) | (pid & (j - 1));
  const int l = i | j;
  const bool up = ((i & k) == 0);
  unsigned long long* a = keys + ((size_t)b << 16);
  const unsigned long long x = a[i], y = a[l];
  if ((x > y) == up) { a[i] = y; a[l] = x; }
}

__global__ __launch_bounds__(1024) void bitonic_finish(unsigned long long* __restrict__ keys,
                                                       int k) {
  __shared__ unsigned long long s[CHUNK];
  const int cb = blockIdx.x;
  unsigned long long* a = keys + (size_t)cb * CHUNK;
  const unsigned gi0 = (unsigned)(cb * CHUNK) & (SORT_M - 1);
  for (int i = threadIdx.x; i < CHUNK; i += 1024) s[i] = a[i];
  __syncthreads();
  const bool up = ((gi0 & k) == 0);
  for (int j = CHUNK >> 1; j > 0; j >>= 1) {
    for (int pid = threadIdx.x; pid < CHUNK / 2; pid += 1024) {
      const int i = ((pid & ~(j - 1)) << 1) | (pid & (j - 1));
      const int l = i | j;
      const unsigned long long x = s[i], y = s[l];
      if ((x > y) == up) { s[i] = y; s[l] = x; }
    }
    __syncthreads();
  }
  for (int i = threadIdx.x; i < CHUNK; i += 1024) a[i] = s[i];
}

// ---------------- write point_coords = [imp(12288), rand(4096)] ----------------
__global__ __launch_bounds__(256) void write_coords(const unsigned long long* __restrict__ keys,
                                                    const float* __restrict__ cand,
                                                    const float* __restrict__ rnd,
                                                    float* __restrict__ outc) {
  const int t = blockIdx.x * blockDim.x + threadIdx.x;
  if (t >= NB * NPTS) return;
  const int nn = t >> 14, p = t & (NPTS - 1);
  float cx, cy;
  if (p < NIMP) {
    const unsigned idx = (unsigned)(keys[((size_t)nn << 16) + p] & 0xFFFFFFFFu);
    const size_t ci = ((size_t)nn * NSAMP + idx) * 2;
    cx = cand[ci]; cy = cand[ci + 1];
  } else {
    const size_t ri = ((size_t)nn * NRAND + (p - NIMP)) * 2;
    cx = rnd[ri]; cy = rnd[ri + 1];
  }
  outc[(size_t)t * 2] = cx;
  outc[(size_t)t * 2 + 1] = cy;
}

// ---------------- weight conversion fp32 -> bf16, K padded 275->288 ----------------
// wbf: [3][256][288], wpb: [32][288] (rows 19..31 zero). Runs after the sort
// (reuses the keys workspace region).
__global__ __launch_bounds__(256) void convert_w(
    const float* __restrict__ w0, const float* __restrict__ w1,
    const float* __restrict__ w2, const float* __restrict__ wpw,
    unsigned short* __restrict__ wbf, unsigned short* __restrict__ wpb) {
  const int i = blockIdx.x * blockDim.x + threadIdx.x;
  if (i < 3 * 256 * KP) {
    const int L = i / (256 * KP);
    const int rem = i - L * (256 * KP);
    const int o = rem / KP, k = rem - o * KP;
    const float* W = (L == 0) ? w0 : (L == 1) ? w1 : w2;
    wbf[i] = (k < FIN) ? f2bf(W[o * FIN + k]) : (unsigned short)0;
  } else if (i < 3 * 256 * KP + 32 * KP) {
    const int j = i - 3 * 256 * KP;
    const int o = j / KP, k = j - o * KP;
    wpb[j] = (o < CCH && k < FIN) ? f2bf(wpw[o * FIN + k]) : (unsigned short)0;
  }
}

// ---------------- fused sample + bf16-MFMA MLP + head ----------------
// 64 points/block, 256 thr (4 waves). Wave w owns output channels [64w,64w+64).
// xp: [64 points][320 bf16] with T2 XOR swizzle (byte ^= (row&7)<<4) so the
// B-fragment ds_read_b128 column-slice is conflict-free (row stride 640B would
// otherwise be a 16-way conflict).
__global__ __launch_bounds__(256, 3) void fused_mfma(
    const float* __restrict__ coarse, const float* __restrict__ feats,
    const float* __restrict__ b0, const float* __restrict__ b1,
    const float* __restrict__ b2, const float* __restrict__ bp,
    const unsigned short* __restrict__ wbf, const unsigned short* __restrict__ wpb,
    const float* __restrict__ pc, float* __restrict__ outl) {
  __shared__ __align__(16) unsigned short xp[TP * (XROW / 2)];   // 40 KB
  __shared__ int   offF[4][TP];  __shared__ float wgtF[4][TP];
  __shared__ int   offC[4][TP];  __shared__ float wgtC[4][TP];

  const int t = threadIdx.x;
  const int nn = blockIdx.x >> 8;
  const int pbase = (blockIdx.x & 255) * TP;

  if (t < TP) {
    const int p = t;
    const size_t ci = ((size_t)nn * NPTS + pbase + p) * 2;
    const float cx = pc[ci], cy = pc[ci + 1];
    {  // fine grid 128x128
      const float X = cx * 128.0f - 0.5f, Y = cy * 128.0f - 0.5f;
      const float x0f = floorf(X), y0f = floorf(Y);
      const float fx = X - x0f, fy = Y - y0f;
      const float wx0 = 1.0f - fx, wy0 = 1.0f - fy;
      const int x0 = (int)x0f, y0 = (int)y0f;
      const int x0c = min(max(x0, 0), 127), x1c = min(max(x0 + 1, 0), 127);
      const int y0c = min(max(y0, 0), 127), y1c = min(max(y0 + 1, 0), 127);
      const bool vx0 = (x0 >= 0) & (x0 <= 127), vx1 = (x0 >= -1) & (x0 <= 126);
      const bool vy0 = (y0 >= 0) & (y0 <= 127), vy1 = (y0 >= -1) & (y0 <= 126);
      offF[0][p] = y0c * 128 + x0c; wgtF[0][p] = (vy0 & vx0) ? wy0 * wx0 : 0.0f;
      offF[1][p] = y0c * 128 + x1c; wgtF[1][p] = (vy0 & vx1) ? wy0 * fx  : 0.0f;
      offF[2][p] = y1c * 128 + x0c; wgtF[2][p] = (vy1 & vx0) ? fy  * wx0 : 0.0f;
      offF[3][p] = y1c * 128 + x1c; wgtF[3][p] = (vy1 & vx1) ? fy  * fx  : 0.0f;
    }
    {  // coarse grid 64x64
      const float X = cx * 64.0f - 0.5f, Y = cy * 64.0f - 0.5f;
      const float x0f = floorf(X), y0f = floorf(Y);
      const float fx = X - x0f, fy = Y - y0f;
      const float wx0 = 1.0f - fx, wy0 = 1.0f - fy;
      const int x0 = (int)x0f, y0 = (int)y0f;
      const int x0c = min(max(x0, 0), 63), x1c = min(max(x0 + 1, 0), 63);
      const int y0c = min(max(y0, 0), 63), y1c = min(max(y0 + 1, 0), 63);
      const bool vx0 = (x0 >= 0) & (x0 <= 63), vx1 = (x0 >= -1) & (x0 <= 62);
      const bool vy0 = (y0 >= 0) & (y0 <= 63), vy1 = (y0 >= -1) & (y0 <= 62);
      offC[0][p] = y0c * 64 + x0c; wgtC[0][p] = (vy0 & vx0) ? wy0 * wx0 : 0.0f;
      offC[1][p] = y0c * 64 + x1c; wgtC[1][p] = (vy0 & vx1) ? wy0 * fx  : 0.0f;
      offC[2][p] = y1c * 64 + x0c; wgtC[2][p] = (vy1 & vx0) ? fy  * wx0 : 0.0f;
      offC[3][p] = y1c * 64 + x1c; wgtC[3][p] = (vy1 & vx1) ? fy  * fx  : 0.0f;
    }
  }
  __syncthreads();

  // ---- gather: fill xp[p][c] for c in [0,288): fine | coarse | zero-pad ----
  for (int i = t; i < (KP / 2) * TP; i += 256) {
    const int p = i & (TP - 1);
    const int c0 = (i >> 6) * 2;
    float v0 = 0.0f, v1 = 0.0f;
    if (c0 < FCH) {
      const float* fb0 = feats + ((size_t)nn << 22) + ((size_t)c0 << 14);
      const float* fb1 = fb0 + 16384;
      const int o0 = offF[0][p], o1 = offF[1][p], o2 = offF[2][p], o3 = offF[3][p];
      const float g0 = wgtF[0][p], g1 = wgtF[1][p], g2 = wgtF[2][p], g3 = wgtF[3][p];
      v0 = ((fb0[o0] * g0 + fb0[o1] * g1) + fb0[o2] * g2) + fb0[o3] * g3;
      v1 = ((fb1[o0] * g0 + fb1[o1] * g1) + fb1[o2] * g2) + fb1[o3] * g3;
    } else if (c0 < FIN) {
      const float* cb0 = coarse + (size_t)nn * (CCH * 4096) + (size_t)(c0 - FCH) * 4096;
      const int o0 = offC[0][p], o1 = offC[1][p], o2 = offC[2][p], o3 = offC[3][p];
      const float g0 = wgtC[0][p], g1 = wgtC[1][p], g2 = wgtC[2][p], g3 = wgtC[3][p];
      v0 = ((cb0[o0] * g0 + cb0[o1] * g1) + cb0[o2] * g2) + cb0[o3] * g3;
      if (c0 + 1 < FIN) {
        const float* cb1 = cb0 + 4096;
        v1 = ((cb1[o0] * g0 + cb1[o1] * g1) + cb1[o2] * g2) + cb1[o3] * g3;
      }
    }
    const uint32_t u = (uint32_t)f2bf(v0) | ((uint32_t)f2bf(v1) << 16);
    *(uint32_t*)((char*)xp + p * XROW + (((unsigned)(c0 * 2)) ^ ((unsigned)(p & 7) << 4))) = u;
  }

  const int lane = t & 63, wave = t >> 6;
  const int l15 = lane & 15, g = lane >> 4;
  const unsigned swz = (unsigned)(l15 & 7) << 4;   // == (row&7)<<4 for all tiles
  const char* xpB = (const char*)xp;

  const float* Bs[3] = {b0, b1, b2};

  for (int L = 0; L < 3; ++L) {
    __syncthreads();   // xp inputs visible (sampling for L=0, epilogue for L>0)
    const unsigned short* wL = wbf + (size_t)L * (256 * KP);
    const unsigned short* wbase = wL + ((size_t)(wave * 64 + l15)) * KP + g * 8;

    f32x4 acc[4][4];
#pragma unroll
    for (int mt = 0; mt < 4; ++mt)
#pragma unroll
      for (int nt = 0; nt < 4; ++nt) acc[mt][nt] = (f32x4)(0.0f);

    for (int ks = 0; ks < 9; ++ks) {
      bf16x8 a0 = *(const bf16x8*)(wbase + 0 * 16 * KP + ks * 32);
      bf16x8 a1 = *(const bf16x8*)(wbase + 1 * 16 * KP + ks * 32);
      bf16x8 a2 = *(const bf16x8*)(wbase + 2 * 16 * KP + ks * 32);
      bf16x8 a3 = *(const bf16x8*)(wbase + 3 * 16 * KP + ks * 32);
      const unsigned kb = (unsigned)(ks * 64 + g * 16) ^ swz;
      bf16x8 q0 = *(const bf16x8*)(xpB + (0 * 16 + l15) * XROW + kb);
      bf16x8 q1 = *(const bf16x8*)(xpB + (1 * 16 + l15) * XROW + kb);
      bf16x8 q2 = *(const bf16x8*)(xpB + (2 * 16 + l15) * XROW + kb);
      bf16x8 q3 = *(const bf16x8*)(xpB + (3 * 16 + l15) * XROW + kb);
#pragma unroll
      for (int nt = 0; nt < 4; ++nt) {
        const bf16x8 bq = (nt == 0) ? q0 : (nt == 1) ? q1 : (nt == 2) ? q2 : q3;
        acc[0][nt] = __builtin_amdgcn_mfma_f32_16x16x32_bf16(a0, bq, acc[0][nt], 0, 0, 0);
        acc[1][nt] = __builtin_amdgcn_mfma_f32_16x16x32_bf16(a1, bq, acc[1][nt], 0, 0, 0);
        acc[2][nt] = __builtin_amdgcn_mfma_f32_16x16x32_bf16(a2, bq, acc[2][nt], 0, 0, 0);
        acc[3][nt] = __builtin_amdgcn_mfma_f32_16x16x32_bf16(a3, bq, acc[3][nt], 0, 0, 0);
      }
    }
    __syncthreads();   // all reads of xp done before overwrite

    const float* __restrict__ Bv = Bs[L];
#pragma unroll
    for (int mt = 0; mt < 4; ++mt) {
      const int ch0 = wave * 64 + mt * 16 + (g << 2);
      const float4 bv = *(const float4*)(Bv + ch0);
#pragma unroll
      for (int nt = 0; nt < 4; ++nt) {
        const int p = nt * 16 + l15;
        const f32x4 v = acc[mt][nt];
        const unsigned short h0 = f2bf(fmaxf(v[0] + bv.x, 0.0f));
        const unsigned short h1 = f2bf(fmaxf(v[1] + bv.y, 0.0f));
        const unsigned short h2 = f2bf(fmaxf(v[2] + bv.z, 0.0f));
        const unsigned short h3 = f2bf(fmaxf(v[3] + bv.w, 0.0f));
        uint2 u;
        u.x = (uint32_t)h0 | ((uint32_t)h1 << 16);
        u.y = (uint32_t)h2 | ((uint32_t)h3 << 16);
        *(uint2*)((char*)xp + p * XROW + (((unsigned)(ch0 * 2)) ^ swz)) = u;
      }
    }
  }
  __syncthreads();   // layer-2 output (head input) visible

  // ---- head: M=32 (19 valid), 8 (mt,nt) pairs over 4 waves, 2 each ----
  const unsigned short* hbase = wpb + (size_t)l15 * KP + g * 8;
  f32x4 hacc0 = (f32x4)(0.0f), hacc1 = (f32x4)(0.0f);
  const int pr0 = wave * 2;
  const int mt0 = pr0 >> 2,       nt0 = pr0 & 3;
  const int mt1 = (pr0 + 1) >> 2, nt1 = (pr0 + 1) & 3;
  for (int ks = 0; ks < 9; ++ks) {
    const unsigned kb = (unsigned)(ks * 64 + g * 16) ^ swz;
    const bf16x8 ha0 = *(const bf16x8*)(hbase + mt0 * 16 * KP + ks * 32);
    const bf16x8 hb0 = *(const bf16x8*)(xpB + (nt0 * 16 + l15) * XROW + kb);
    hacc0 = __builtin_amdgcn_mfma_f32_16x16x32_bf16(ha0, hb0, hacc0, 0, 0, 0);
    const bf16x8 ha1 = *(const bf16x8*)(hbase + mt1 * 16 * KP + ks * 32);
    const bf16x8 hb1 = *(const bf16x8*)(xpB + (nt1 * 16 + l15) * XROW + kb);
    hacc1 = __builtin_amdgcn_mfma_f32_16x16x32_bf16(ha1, hb1, hacc1, 0, 0, 0);
  }
#pragma unroll
  for (int q = 0; q < 2; ++q) {
    const f32x4 v = q ? hacc1 : hacc0;
    const int mt = q ? mt1 : mt0, nt = q ? nt1 : nt0;
    const int p = pbase + nt * 16 + l15;
#pragma unroll
    for (int j = 0; j < 4; ++j) {
      const int ch = mt * 16 + (g << 2) + j;
      if (ch < CCH)
        outl[((size_t)nn * CCH + ch) * NPTS + p] = v[j] + bp[ch];
    }
  }
}

// ---------------- launcher ----------------
extern "C" void kernel_launch(void* const* d_in, const int* in_sizes, int n_in,
                              void* d_out, int out_size, void* d_ws, size_t ws_size,
                              hipStream_t stream) {
  const float* coarse = (const float*)d_in[0];
  const float* feats  = (const float*)d_in[1];
  const float* w0 = (const float*)d_in[2]; const float* b0 = (const float*)d_in[3];
  const float* w1 = (const float*)d_in[4]; const float* b1 = (const float*)d_in[5];
  const float* w2 = (const float*)d_in[6]; const float* b2 = (const float*)d_in[7];
  const float* wp = (const float*)d_in[8]; const float* bp = (const float*)d_in[9];

  float* out0 = (float*)d_out;
  float* outL = out0 + 622592;
  float* outC = outL + 2490368;

  float* cand = (float*)d_ws;                          // 786432 f32
  float* rnd  = cand + 786432;                         // 65536 f32
  unsigned long long* keys =
      (unsigned long long*)((char*)d_ws + 3407872);    // 8*65536 u64
  // bf16 weights REUSE the keys region (sort consumed before convert_w runs):
  unsigned short* wbf = (unsigned short*)((char*)d_ws + 3407872);  // 3*256*288
  unsigned short* wpb = wbf + 3 * 256 * KP;                        // 32*288

  uint32_t k1a, k1b, k2a, k2b;
#if RNG_MODE == 0
  uint32_t f0, s0, f1, s1;
  tf2x32(0u, 7u, 0u, 2u, &f0, &s0);
  tf2x32(0u, 7u, 1u, 3u, &f1, &s1);
  k1a = f0; k1b = f1; k2a = s0; k2b = s1;
#else
  tf2x32(0u, 7u, 0u, 0u, &k1a, &k1b);
  tf2x32(0u, 7u, 0u, 1u, &k2a, &k2b);
#endif

  hipMemcpyAsync(out0, coarse, 622592 * sizeof(float),
                 hipMemcpyDeviceToDevice, stream);

#if RNG_MODE == 0
  gen_uniform_orig<<<(393216 + 255) / 256, 256, 0, stream>>>(cand, 393216u, k1a, k1b);
  gen_uniform_orig<<<(32768 + 255) / 256, 256, 0, stream>>>(rnd, 32768u, k2a, k2b);
#else
  gen_uniform_part<<<786432 / 256, 256, 0, stream>>>(cand, 786432u, k1a, k1b);
  gen_uniform_part<<<65536 / 256, 256, 0, stream>>>(rnd, 65536u, k2a, k2b);
#endif

  unc_keys<<<2048, 256, 0, stream>>>(coarse, cand, keys);

  bitonic_local<<<64, 1024, 0, stream>>>(keys);
  bitonic_global<<<1024, 256, 0, stream>>>(keys, 16384, 8192);
  bitonic_finish<<<64, 1024, 0, stream>>>(keys, 16384);
  bitonic_global<<<1024, 256, 0, stream>>>(keys, 32768, 16384);
  bitonic_global<<<1024, 256, 0, stream>>>(keys, 32768, 8192);
  bitonic_finish<<<64, 1024, 0, stream>>>(keys, 32768);
  bitonic_global<<<1024, 256, 0, stream>>>(keys, 65536, 32768);
  bitonic_global<<<1024, 256, 0, stream>>>(keys, 65536, 16384);
  bitonic_global<<<1024, 256, 0, stream>>>(keys, 65536, 8192);
  bitonic_finish<<<64, 1024, 0, stream>>>(keys, 65536);

  write_coords<<<512, 256, 0, stream>>>(keys, cand, rnd, outC);

  // convert weights AFTER the sort (reuses keys region)
  convert_w<<<(3 * 256 * KP + 32 * KP + 255) / 256, 256, 0, stream>>>(
      w0, w1, w2, wp, wbf, wpb);

  fused_mfma<<<2048, 256, 0, stream>>>(coarse, feats, b0, b1, b2, bp,
                                       wbf, wpb, outC, outL);
}

// Round 6
// 396.418 us; speedup vs baseline: 7.4075x; 1.6828x over previous
//
#include <hip/hip_runtime.h>
#include <stdint.h>

// Contraction off file-wide: the uncertainty path drives top-k SELECTION ORDER
// and must be bit-identical to the JAX/numpy reference (mul+add, no fma).
// Explicit fmaf() calls (GEMM/gather for the logits path) are unaffected.
#pragma clang fp contract(off)

#define RNG_MODE 1

#define NB    8
#define CCH   19
#define FCH   256
#define FIN   275
#define KP    288      // K padded to 9*32
#define NPTS  16384
#define NSAMP 49152
#define NIMP  12288
#define NRAND 4096
#define SORT_M 65536
#define CHUNK  8192
#define TP    64       // points per block in fused MFMA head
#define XROW  640      // bytes per xp row (320 bf16), 128B-multiple for swizzle
#define FTR_OFF (8u << 20)                  // ws offset of transposed features
#define FTR_BYTES (134217728ull / 2)        // 8*16384*256*2 = 64 MiB

typedef __attribute__((ext_vector_type(8))) short bf16x8;
typedef __attribute__((ext_vector_type(4))) float f32x4;

// ---------------- threefry2x32 (exact JAX algorithm) ----------------
__host__ __device__ __forceinline__ uint32_t rotl32(uint32_t v, int r) {
  return (v << r) | (v >> (32 - r));
}

__host__ __device__ __forceinline__ void tf2x32(uint32_t k0, uint32_t k1,
                                                uint32_t x0, uint32_t x1,
                                                uint32_t* o0, uint32_t* o1) {
  const uint32_t ks2 = k0 ^ k1 ^ 0x1BD11BDAu;
  x0 += k0; x1 += k1;
#define TF_R(r) { x0 += x1; x1 = rotl32(x1, (r)); x1 ^= x0; }
  TF_R(13) TF_R(15) TF_R(26) TF_R(6)
  x0 += k1;  x1 += ks2 + 1u;
  TF_R(17) TF_R(29) TF_R(16) TF_R(24)
  x0 += ks2; x1 += k0 + 2u;
  TF_R(13) TF_R(15) TF_R(26) TF_R(6)
  x0 += k0;  x1 += k1 + 3u;
  TF_R(17) TF_R(29) TF_R(16) TF_R(24)
  x0 += k1;  x1 += ks2 + 4u;
  TF_R(13) TF_R(15) TF_R(26) TF_R(6)
  x0 += ks2; x1 += k0 + 5u;
#undef TF_R
  *o0 = x0; *o1 = x1;
}

__device__ __forceinline__ float u01(uint32_t b) {
  const float f = __uint_as_float((b >> 9) | 0x3f800000u) - 1.0f;
  return fmaxf(0.0f, f);
}

__device__ __forceinline__ unsigned short f2bf(float f) {
  // round-to-nearest-even fp32 -> bf16
  const uint32_t u = __float_as_uint(f);
  return (unsigned short)((u + 0x7fffu + ((u >> 16) & 1u)) >> 16);
}

__device__ __forceinline__ float bf2f(unsigned short h) {
  return __uint_as_float((uint32_t)h << 16);
}

__global__ __launch_bounds__(256) void gen_uniform_part(float* __restrict__ out,
                                                        unsigned n, uint32_t k0, uint32_t k1) {
  const unsigned i = blockIdx.x * blockDim.x + threadIdx.x;
  if (i >= n) return;
  uint32_t o0, o1;
  tf2x32(k0, k1, 0u, i, &o0, &o1);
  out[i] = u01(o0 ^ o1);
}

__global__ __launch_bounds__(256) void gen_uniform_orig(float* __restrict__ out,
                                                        unsigned half, uint32_t k0, uint32_t k1) {
  const unsigned j = blockIdx.x * blockDim.x + threadIdx.x;
  if (j >= half) return;
  uint32_t o0, o1;
  tf2x32(k0, k1, j, j + half, &o0, &o1);
  out[j] = u01(o0);
  out[j + half] = u01(o1);
}

// ---------------- uncertainty at candidates -> sortable keys ----------------
__global__ __launch_bounds__(256) void unc_keys(const float* __restrict__ coarse,
                                                const float* __restrict__ cand,
                                                unsigned long long* __restrict__ keys) {
  const int tid = blockIdx.x * blockDim.x + threadIdx.x;
  if (tid >= NB * SORT_M) return;
  const int nn = tid >> 16, s = tid & (SORT_M - 1);
  if (s >= NSAMP) { keys[tid] = 0xFFFFFFFFFFFFFFFFull; return; }
  const size_t ci = ((size_t)nn * NSAMP + s) * 2;
  const float cx = cand[ci], cy = cand[ci + 1];
  const float X = cx * 64.0f - 0.5f, Y = cy * 64.0f - 0.5f;
  const float x0f = floorf(X), y0f = floorf(Y);
  const float fx = X - x0f, fy = Y - y0f;
  const float wx0 = 1.0f - fx, wy0 = 1.0f - fy;
  const int x0 = (int)x0f, y0 = (int)y0f;
  const int x0c = min(max(x0, 0), 63), x1c = min(max(x0 + 1, 0), 63);
  const int y0c = min(max(y0, 0), 63), y1c = min(max(y0 + 1, 0), 63);
  const bool vx0 = (x0 >= 0) & (x0 <= 63), vx1 = (x0 >= -1) & (x0 <= 62);
  const bool vy0 = (y0 >= 0) & (y0 <= 63), vy1 = (y0 >= -1) & (y0 <= 62);
  const float w00 = (vy0 & vx0) ? wy0 * wx0 : 0.0f;
  const float w01 = (vy0 & vx1) ? wy0 * fx  : 0.0f;
  const float w10 = (vy1 & vx0) ? fy  * wx0 : 0.0f;
  const float w11 = (vy1 & vx1) ? fy  * fx  : 0.0f;
  const int o00 = y0c * 64 + x0c, o01 = y0c * 64 + x1c;
  const int o10 = y1c * 64 + x0c, o11 = y1c * 64 + x1c;
  const float* cb = coarse + (size_t)nn * (CCH * 4096);
  float m1 = -3.402823466e38f, m2 = -3.402823466e38f;
  for (int c = 0; c < CCH; ++c) {
    const float* pch = cb + (size_t)c * 4096;
    const float v = ((pch[o00] * w00 + pch[o01] * w01) + pch[o10] * w10) + pch[o11] * w11;
    if (v > m1) { m2 = m1; m1 = v; } else if (v > m2) { m2 = v; }
  }
  const float unc = m2 - m1;
  const uint32_t b = __float_as_uint(unc);
  const uint32_t asc = (b & 0x80000000u) ? ~b : (b | 0x80000000u);
  keys[tid] = ((unsigned long long)(~asc) << 32) | (uint32_t)s;
}

// ---------------- bitonic sort (per batch of 65536 u64 keys) ----------------
__global__ __launch_bounds__(1024) void bitonic_local(unsigned long long* __restrict__ keys) {
  __shared__ unsigned long long s[CHUNK];
  const int cb = blockIdx.x;
  unsigned long long* a = keys + (size_t)cb * CHUNK;
  const unsigned gbase = (unsigned)(cb * CHUNK) & (SORT_M - 1);
  for (int i = threadIdx.x; i < CHUNK; i += 1024) s[i] = a[i];
  __syncthreads();
  for (int k = 2; k <= CHUNK; k <<= 1) {
    for (int j = k >> 1; j > 0; j >>= 1) {
      for (int pid = threadIdx.x; pid < CHUNK / 2; pid += 1024) {
        const int i = ((pid & ~(j - 1)) << 1) | (pid & (j - 1));
        const int l = i | j;
        const bool up = (((gbase + i) & k) == 0);
        const unsigned long long x = s[i], y = s[l];
        if ((x > y) == up) { s[i] = y; s[l] = x; }
      }
      __syncthreads();
    }
  }
  for (int i = threadIdx.x; i < CHUNK; i += 1024) a[i] = s[i];
}

__global__ __launch_bounds__(256) void bitonic_global(unsigned long long* __restrict__ keys,
                                                      int k, int j) {
  const int t = blockIdx.x * blockDim.x + threadIdx.x;
  const int b = t >> 15, pid = t & 32767;
  const int i = ((pid & ~(j - 1)) << 1) | (pid & (j - 1));
  const int l = i | j;
  const bool up = ((i & k) == 0);
  unsigned long long* a = keys + ((size_t)b << 16);
  const unsigned long long x = a[i], y = a[l];
  if ((x > y) == up) { a[i] = y; a[l] = x; }
}

__global__ __launch_bounds__(1024) void bitonic_finish(unsigned long long* __restrict__ keys,
                                                       int k) {
  __shared__ unsigned long long s[CHUNK];
  const int cb = blockIdx.x;
  unsigned long long* a = keys + (size_t)cb * CHUNK;
  const unsigned gi0 = (unsigned)(cb * CHUNK) & (SORT_M - 1);
  for (int i = threadIdx.x; i < CHUNK; i += 1024) s[i] = a[i];
  __syncthreads();
  const bool up = ((gi0 & k) == 0);
  for (int j = CHUNK >> 1; j > 0; j >>= 1) {
    for (int pid = threadIdx.x; pid < CHUNK / 2; pid += 1024) {
      const int i = ((pid & ~(j - 1)) << 1) | (pid & (j - 1));
      const int l = i | j;
      const unsigned long long x = s[i], y = s[l];
      if ((x > y) == up) { s[i] = y; s[l] = x; }
    }
    __syncthreads();
  }
  for (int i = threadIdx.x; i < CHUNK; i += 1024) a[i] = s[i];
}

// ---------------- write point_coords = [imp(12288), rand(4096)] ----------------
__global__ __launch_bounds__(256) void write_coords(const unsigned long long* __restrict__ keys,
                                                    const float* __restrict__ cand,
                                                    const float* __restrict__ rnd,
                                                    float* __restrict__ outc) {
  const int t = blockIdx.x * blockDim.x + threadIdx.x;
  if (t >= NB * NPTS) return;
  const int nn = t >> 14, p = t & (NPTS - 1);
  float cx, cy;
  if (p < NIMP) {
    const unsigned idx = (unsigned)(keys[((size_t)nn << 16) + p] & 0xFFFFFFFFu);
    const size_t ci = ((size_t)nn * NSAMP + idx) * 2;
    cx = cand[ci]; cy = cand[ci + 1];
  } else {
    const size_t ri = ((size_t)nn * NRAND + (p - NIMP)) * 2;
    cx = rnd[ri]; cy = rnd[ri + 1];
  }
  outc[(size_t)t * 2] = cx;
  outc[(size_t)t * 2 + 1] = cy;
}

// ---------------- weight conversion fp32 -> bf16, K padded 275->288 ----------------
__global__ __launch_bounds__(256) void convert_w(
    const float* __restrict__ w0, const float* __restrict__ w1,
    const float* __restrict__ w2, const float* __restrict__ wpw,
    unsigned short* __restrict__ wbf, unsigned short* __restrict__ wpb) {
  const int i = blockIdx.x * blockDim.x + threadIdx.x;
  if (i < 3 * 256 * KP) {
    const int L = i / (256 * KP);
    const int rem = i - L * (256 * KP);
    const int o = rem / KP, k = rem - o * KP;
    const float* W = (L == 0) ? w0 : (L == 1) ? w1 : w2;
    wbf[i] = (k < FIN) ? f2bf(W[o * FIN + k]) : (unsigned short)0;
  } else if (i < 3 * 256 * KP + 32 * KP) {
    const int j = i - 3 * 256 * KP;
    const int o = j / KP, k = j - o * KP;
    wpb[j] = (o < CCH && k < FIN) ? f2bf(wpw[o * FIN + k]) : (unsigned short)0;
  }
}

// ---------------- features transpose: (N,C,128,128) f32 -> (N,16384,C) bf16 ----
// Tile 64ch x 64px. LDS row stride 66 ushort (33 dwords) => bank = p mod 32,
// conflict-free (2-way only) in both phases.
__global__ __launch_bounds__(256) void transpose_feats(
    const float* __restrict__ feats, unsigned short* __restrict__ ftr) {
  __shared__ unsigned short tile[64][66];
  const int b = blockIdx.x;              // 8 * 4 * 256
  const int nn = b >> 10;
  const int ct = (b >> 8) & 3;
  const int pt = b & 255;
  const int c0 = ct * 64, p0 = pt * 64;
  const int t = threadIdx.x;
  const float* src = feats + ((size_t)nn << 22);
#pragma unroll 4
  for (int k = 0; k < 16; ++k) {
    const int c = 4 * k + (t >> 6);      // 0..63
    const int p = t & 63;
    tile[p][c] = f2bf(src[((size_t)(c0 + c) << 14) + p0 + p]);
  }
  __syncthreads();
  const int p = t >> 2, q = t & 3;       // 64 px, 16 ch each
  const int cb = q * 16;
  uint32_t w[8];
#pragma unroll
  for (int m = 0; m < 8; ++m)
    w[m] = (uint32_t)tile[p][cb + 2 * m] | ((uint32_t)tile[p][cb + 2 * m + 1] << 16);
  unsigned short* dst = ftr + ((((size_t)nn << 14) + p0 + p) << 8) + c0 + cb;
  *(uint4*)(dst)     = make_uint4(w[0], w[1], w[2], w[3]);
  *(uint4*)(dst + 8) = make_uint4(w[4], w[5], w[6], w[7]);
}

// ---------------- fused sample + bf16-MFMA MLP + head ----------------
// USE_TR=1: fine features gathered from transposed bf16 ftr (coalesced 512B
// rows, b128 loads). USE_TR=0: round-5 scattered fp32 gather (ws fallback).
template <int USE_TR>
__global__ __launch_bounds__(256, 3) void fused_mfma(
    const float* __restrict__ coarse, const float* __restrict__ feats,
    const unsigned short* __restrict__ ftr,
    const float* __restrict__ b0, const float* __restrict__ b1,
    const float* __restrict__ b2, const float* __restrict__ bp,
    const unsigned short* __restrict__ wbf, const unsigned short* __restrict__ wpb,
    const float* __restrict__ pc, float* __restrict__ outl) {
  __shared__ __align__(16) unsigned short xp[TP * (XROW / 2)];   // 40 KB
  __shared__ int   offF[4][TP];  __shared__ float wgtF[4][TP];
  __shared__ int   offC[4][TP];  __shared__ float wgtC[4][TP];

  const int t = threadIdx.x;
  const int nn = blockIdx.x >> 8;
  const int pbase = (blockIdx.x & 255) * TP;

  if (t < TP) {
    const int p = t;
    const size_t ci = ((size_t)nn * NPTS + pbase + p) * 2;
    const float cx = pc[ci], cy = pc[ci + 1];
    {  // fine grid 128x128
      const float X = cx * 128.0f - 0.5f, Y = cy * 128.0f - 0.5f;
      const float x0f = floorf(X), y0f = floorf(Y);
      const float fx = X - x0f, fy = Y - y0f;
      const float wx0 = 1.0f - fx, wy0 = 1.0f - fy;
      const int x0 = (int)x0f, y0 = (int)y0f;
      const int x0c = min(max(x0, 0), 127), x1c = min(max(x0 + 1, 0), 127);
      const int y0c = min(max(y0, 0), 127), y1c = min(max(y0 + 1, 0), 127);
      const bool vx0 = (x0 >= 0) & (x0 <= 127), vx1 = (x0 >= -1) & (x0 <= 126);
      const bool vy0 = (y0 >= 0) & (y0 <= 127), vy1 = (y0 >= -1) & (y0 <= 126);
      offF[0][p] = y0c * 128 + x0c; wgtF[0][p] = (vy0 & vx0) ? wy0 * wx0 : 0.0f;
      offF[1][p] = y0c * 128 + x1c; wgtF[1][p] = (vy0 & vx1) ? wy0 * fx  : 0.0f;
      offF[2][p] = y1c * 128 + x0c; wgtF[2][p] = (vy1 & vx0) ? fy  * wx0 : 0.0f;
      offF[3][p] = y1c * 128 + x1c; wgtF[3][p] = (vy1 & vx1) ? fy  * fx  : 0.0f;
    }
    {  // coarse grid 64x64
      const float X = cx * 64.0f - 0.5f, Y = cy * 64.0f - 0.5f;
      const float x0f = floorf(X), y0f = floorf(Y);
      const float fx = X - x0f, fy = Y - y0f;
      const float wx0 = 1.0f - fx, wy0 = 1.0f - fy;
      const int x0 = (int)x0f, y0 = (int)y0f;
      const int x0c = min(max(x0, 0), 63), x1c = min(max(x0 + 1, 0), 63);
      const int y0c = min(max(y0, 0), 63), y1c = min(max(y0 + 1, 0), 63);
      const bool vx0 = (x0 >= 0) & (x0 <= 63), vx1 = (x0 >= -1) & (x0 <= 62);
      const bool vy0 = (y0 >= 0) & (y0 <= 63), vy1 = (y0 >= -1) & (y0 <= 62);
      offC[0][p] = y0c * 64 + x0c; wgtC[0][p] = (vy0 & vx0) ? wy0 * wx0 : 0.0f;
      offC[1][p] = y0c * 64 + x1c; wgtC[1][p] = (vy0 & vx1) ? wy0 * fx  : 0.0f;
      offC[2][p] = y1c * 64 + x0c; wgtC[2][p] = (vy1 & vx0) ? fy  * wx0 : 0.0f;
      offC[3][p] = y1c * 64 + x1c; wgtC[3][p] = (vy1 & vx1) ? fy  * fx  : 0.0f;
    }
  }
  __syncthreads();

  if (USE_TR) {
    // ---- fine gather from transposed bf16: 4 thr/point, 64 ch each ----
    const int p = t >> 2, q = t & 3;
    const unsigned short* base = ftr + (((size_t)nn << 14) << 8) + q * 64;
    const unsigned short* n0 = base + ((size_t)offF[0][p] << 8);
    const unsigned short* n1 = base + ((size_t)offF[1][p] << 8);
    const unsigned short* n2 = base + ((size_t)offF[2][p] << 8);
    const unsigned short* n3 = base + ((size_t)offF[3][p] << 8);
    const float g0 = wgtF[0][p], g1 = wgtF[1][p], g2 = wgtF[2][p], g3 = wgtF[3][p];
    const unsigned swzp = (unsigned)(p & 7) << 4;
#pragma unroll
    for (int m = 0; m < 8; ++m) {
      const bf16x8 a = *(const bf16x8*)(n0 + m * 8);
      const bf16x8 bq = *(const bf16x8*)(n1 + m * 8);
      const bf16x8 c = *(const bf16x8*)(n2 + m * 8);
      const bf16x8 d = *(const bf16x8*)(n3 + m * 8);
      uint32_t u[4];
#pragma unroll
      for (int e = 0; e < 4; ++e) {
        float v0 = fmaf(bf2f((unsigned short)a[2 * e]), g0,
                   fmaf(bf2f((unsigned short)bq[2 * e]), g1,
                   fmaf(bf2f((unsigned short)c[2 * e]), g2,
                        bf2f((unsigned short)d[2 * e]) * g3)));
        float v1 = fmaf(bf2f((unsigned short)a[2 * e + 1]), g0,
                   fmaf(bf2f((unsigned short)bq[2 * e + 1]), g1,
                   fmaf(bf2f((unsigned short)c[2 * e + 1]), g2,
                        bf2f((unsigned short)d[2 * e + 1]) * g3)));
        u[e] = (uint32_t)f2bf(v0) | ((uint32_t)f2bf(v1) << 16);
      }
      *(uint4*)((char*)xp + p * XROW + (((unsigned)((q * 64 + m * 8) * 2)) ^ swzp)) =
          make_uint4(u[0], u[1], u[2], u[3]);
    }
  }

  // ---- remaining channels (all 288 if !USE_TR, else 256..287) ----
  for (int i = (USE_TR ? 8192 : 0) + t; i < (KP / 2) * TP; i += 256) {
    const int p = i & (TP - 1);
    const int c0 = (i >> 6) * 2;
    float v0 = 0.0f, v1 = 0.0f;
    if (c0 < FCH) {   // only reachable when !USE_TR
      const float* fb0 = feats + ((size_t)nn << 22) + ((size_t)c0 << 14);
      const float* fb1 = fb0 + 16384;
      const int o0 = offF[0][p], o1 = offF[1][p], o2 = offF[2][p], o3 = offF[3][p];
      const float g0 = wgtF[0][p], g1 = wgtF[1][p], g2 = wgtF[2][p], g3 = wgtF[3][p];
      v0 = ((fb0[o0] * g0 + fb0[o1] * g1) + fb0[o2] * g2) + fb0[o3] * g3;
      v1 = ((fb1[o0] * g0 + fb1[o1] * g1) + fb1[o2] * g2) + fb1[o3] * g3;
    } else if (c0 < FIN) {
      const float* cb0 = coarse + (size_t)nn * (CCH * 4096) + (size_t)(c0 - FCH) * 4096;
      const int o0 = offC[0][p], o1 = offC[1][p], o2 = offC[2][p], o3 = offC[3][p];
      const float g0 = wgtC[0][p], g1 = wgtC[1][p], g2 = wgtC[2][p], g3 = wgtC[3][p];
      v0 = ((cb0[o0] * g0 + cb0[o1] * g1) + cb0[o2] * g2) + cb0[o3] * g3;
      if (c0 + 1 < FIN) {
        const float* cb1 = cb0 + 4096;
        v1 = ((cb1[o0] * g0 + cb1[o1] * g1) + cb1[o2] * g2) + cb1[o3] * g3;
      }
    }
    const uint32_t u = (uint32_t)f2bf(v0) | ((uint32_t)f2bf(v1) << 16);
    *(uint32_t*)((char*)xp + p * XROW + (((unsigned)(c0 * 2)) ^ ((unsigned)(p & 7) << 4))) = u;
  }

  const int lane = t & 63, wave = t >> 6;
  const int l15 = lane & 15, g = lane >> 4;
  const unsigned swz = (unsigned)(l15 & 7) << 4;
  const char* xpB = (const char*)xp;

  const float* Bs[3] = {b0, b1, b2};

  for (int L = 0; L < 3; ++L) {
    __syncthreads();
    const unsigned short* wL = wbf + (size_t)L * (256 * KP);
    const unsigned short* wbase = wL + ((size_t)(wave * 64 + l15)) * KP + g * 8;

    f32x4 acc[4][4];
#pragma unroll
    for (int mt = 0; mt < 4; ++mt)
#pragma unroll
      for (int nt = 0; nt < 4; ++nt) acc[mt][nt] = (f32x4)(0.0f);

    for (int ks = 0; ks < 9; ++ks) {
      bf16x8 a0 = *(const bf16x8*)(wbase + 0 * 16 * KP + ks * 32);
      bf16x8 a1 = *(const bf16x8*)(wbase + 1 * 16 * KP + ks * 32);
      bf16x8 a2 = *(const bf16x8*)(wbase + 2 * 16 * KP + ks * 32);
      bf16x8 a3 = *(const bf16x8*)(wbase + 3 * 16 * KP + ks * 32);
      const unsigned kb = (unsigned)(ks * 64 + g * 16) ^ swz;
      bf16x8 q0 = *(const bf16x8*)(xpB + (0 * 16 + l15) * XROW + kb);
      bf16x8 q1 = *(const bf16x8*)(xpB + (1 * 16 + l15) * XROW + kb);
      bf16x8 q2 = *(const bf16x8*)(xpB + (2 * 16 + l15) * XROW + kb);
      bf16x8 q3 = *(const bf16x8*)(xpB + (3 * 16 + l15) * XROW + kb);
#pragma unroll
      for (int nt = 0; nt < 4; ++nt) {
        const bf16x8 bq = (nt == 0) ? q0 : (nt == 1) ? q1 : (nt == 2) ? q2 : q3;
        acc[0][nt] = __builtin_amdgcn_mfma_f32_16x16x32_bf16(a0, bq, acc[0][nt], 0, 0, 0);
        acc[1][nt] = __builtin_amdgcn_mfma_f32_16x16x32_bf16(a1, bq, acc[1][nt], 0, 0, 0);
        acc[2][nt] = __builtin_amdgcn_mfma_f32_16x16x32_bf16(a2, bq, acc[2][nt], 0, 0, 0);
        acc[3][nt] = __builtin_amdgcn_mfma_f32_16x16x32_bf16(a3, bq, acc[3][nt], 0, 0, 0);
      }
    }
    __syncthreads();

    const float* __restrict__ Bv = Bs[L];
#pragma unroll
    for (int mt = 0; mt < 4; ++mt) {
      const int ch0 = wave * 64 + mt * 16 + (g << 2);
      const float4 bv = *(const float4*)(Bv + ch0);
#pragma unroll
      for (int nt = 0; nt < 4; ++nt) {
        const int p = nt * 16 + l15;
        const f32x4 v = acc[mt][nt];
        const unsigned short h0 = f2bf(fmaxf(v[0] + bv.x, 0.0f));
        const unsigned short h1 = f2bf(fmaxf(v[1] + bv.y, 0.0f));
        const unsigned short h2 = f2bf(fmaxf(v[2] + bv.z, 0.0f));
        const unsigned short h3 = f2bf(fmaxf(v[3] + bv.w, 0.0f));
        uint2 u;
        u.x = (uint32_t)h0 | ((uint32_t)h1 << 16);
        u.y = (uint32_t)h2 | ((uint32_t)h3 << 16);
        *(uint2*)((char*)xp + p * XROW + (((unsigned)(ch0 * 2)) ^ swz)) = u;
      }
    }
  }
  __syncthreads();

  // ---- head: M=32 (19 valid), 8 (mt,nt) pairs over 4 waves, 2 each ----
  const unsigned short* hbase = wpb + (size_t)l15 * KP + g * 8;
  f32x4 hacc0 = (f32x4)(0.0f), hacc1 = (f32x4)(0.0f);
  const int pr0 = wave * 2;
  const int mt0 = pr0 >> 2,       nt0 = pr0 & 3;
  const int mt1 = (pr0 + 1) >> 2, nt1 = (pr0 + 1) & 3;
  for (int ks = 0; ks < 9; ++ks) {
    const unsigned kb = (unsigned)(ks * 64 + g * 16) ^ swz;
    const bf16x8 ha0 = *(const bf16x8*)(hbase + mt0 * 16 * KP + ks * 32);
    const bf16x8 hb0 = *(const bf16x8*)(xpB + (nt0 * 16 + l15) * XROW + kb);
    hacc0 = __builtin_amdgcn_mfma_f32_16x16x32_bf16(ha0, hb0, hacc0, 0, 0, 0);
    const bf16x8 ha1 = *(const bf16x8*)(hbase + mt1 * 16 * KP + ks * 32);
    const bf16x8 hb1 = *(const bf16x8*)(xpB + (nt1 * 16 + l15) * XROW + kb);
    hacc1 = __builtin_amdgcn_mfma_f32_16x16x32_bf16(ha1, hb1, hacc1, 0, 0, 0);
  }
#pragma unroll
  for (int q = 0; q < 2; ++q) {
    const f32x4 v = q ? hacc1 : hacc0;
    const int mt = q ? mt1 : mt0, nt = q ? nt1 : nt0;
    const int p = pbase + nt * 16 + l15;
#pragma unroll
    for (int j = 0; j < 4; ++j) {
      const int ch = mt * 16 + (g << 2) + j;
      if (ch < CCH)
        outl[((size_t)nn * CCH + ch) * NPTS + p] = v[j] + bp[ch];
    }
  }
}

// ---------------- launcher ----------------
extern "C" void kernel_launch(void* const* d_in, const int* in_sizes, int n_in,
                              void* d_out, int out_size, void* d_ws, size_t ws_size,
                              hipStream_t stream) {
  const float* coarse = (const float*)d_in[0];
  const float* feats  = (const float*)d_in[1];
  const float* w0 = (const float*)d_in[2]; const float* b0 = (const float*)d_in[3];
  const float* w1 = (const float*)d_in[4]; const float* b1 = (const float*)d_in[5];
  const float* w2 = (const float*)d_in[6]; const float* b2 = (const float*)d_in[7];
  const float* wp = (const float*)d_in[8]; const float* bp = (const float*)d_in[9];

  float* out0 = (float*)d_out;
  float* outL = out0 + 622592;
  float* outC = outL + 2490368;

  float* cand = (float*)d_ws;                          // 786432 f32
  float* rnd  = cand + 786432;                         // 65536 f32
  unsigned long long* keys =
      (unsigned long long*)((char*)d_ws + 3407872);    // 8*65536 u64
  unsigned short* wbf = (unsigned short*)((char*)d_ws + 3407872);  // reuse keys
  unsigned short* wpb = wbf + 3 * 256 * KP;
  unsigned short* ftr = (unsigned short*)((char*)d_ws + FTR_OFF); // 64 MiB
  const bool use_tr = ws_size >= (size_t)FTR_OFF + FTR_BYTES;

  uint32_t k1a, k1b, k2a, k2b;
#if RNG_MODE == 0
  uint32_t f0, s0, f1, s1;
  tf2x32(0u, 7u, 0u, 2u, &f0, &s0);
  tf2x32(0u, 7u, 1u, 3u, &f1, &s1);
  k1a = f0; k1b = f1; k2a = s0; k2b = s1;
#else
  tf2x32(0u, 7u, 0u, 0u, &k1a, &k1b);
  tf2x32(0u, 7u, 0u, 1u, &k2a, &k2b);
#endif

  hipMemcpyAsync(out0, coarse, 622592 * sizeof(float),
                 hipMemcpyDeviceToDevice, stream);

  if (use_tr)
    transpose_feats<<<8192, 256, 0, stream>>>(feats, ftr);

#if RNG_MODE == 0
  gen_uniform_orig<<<(393216 + 255) / 256, 256, 0, stream>>>(cand, 393216u, k1a, k1b);
  gen_uniform_orig<<<(32768 + 255) / 256, 256, 0, stream>>>(rnd, 32768u, k2a, k2b);
#else
  gen_uniform_part<<<786432 / 256, 256, 0, stream>>>(cand, 786432u, k1a, k1b);
  gen_uniform_part<<<65536 / 256, 256, 0, stream>>>(rnd, 65536u, k2a, k2b);
#endif

  unc_keys<<<2048, 256, 0, stream>>>(coarse, cand, keys);

  bitonic_local<<<64, 1024, 0, stream>>>(keys);
  bitonic_global<<<1024, 256, 0, stream>>>(keys, 16384, 8192);
  bitonic_finish<<<64, 1024, 0, stream>>>(keys, 16384);
  bitonic_global<<<1024, 256, 0, stream>>>(keys, 32768, 16384);
  bitonic_global<<<1024, 256, 0, stream>>>(keys, 32768, 8192);
  bitonic_finish<<<64, 1024, 0, stream>>>(keys, 32768);
  bitonic_global<<<1024, 256, 0, stream>>>(keys, 65536, 32768);
  bitonic_global<<<1024, 256, 0, stream>>>(keys, 65536, 16384);
  bitonic_global<<<1024, 256, 0, stream>>>(keys, 65536, 8192);
  bitonic_finish<<<64, 1024, 0, stream>>>(keys, 65536);

  write_coords<<<512, 256, 0, stream>>>(keys, cand, rnd, outC);

  convert_w<<<(3 * 256 * KP + 32 * KP + 255) / 256, 256, 0, stream>>>(
      w0, w1, w2, wp, wbf, wpb);

  if (use_tr)
    fused_mfma<1><<<2048, 256, 0, stream>>>(coarse, feats, ftr, b0, b1, b2, bp,
                                            wbf, wpb, outC, outL);
  else
    fused_mfma<0><<<2048, 256, 0, stream>>>(coarse, feats, ftr, b0, b1, b2, bp,
                                            wbf, wpb, outC, outL);
}